// Round 1
// baseline (504.870 us; speedup 1.0000x reference)
//
#include <hip/hip_runtime.h>
#include <hip/hip_bf16.h>

#define IN_CH   128
#define HID_CH  256
#define KTOT    256   // concat K: [agg | x]
#define KB      32    // K chunk staged in LDS
#define TN      64    // nodes per block
#define TJ      64    // out channels per block
#define LDSPAD  68    // row stride in floats (keeps 16B align, breaks bank pattern)

// ---------------- scatter: agg[dst] += x[src], deg[dst] += 1 ----------------
__global__ __launch_bounds__(256) void scatter_kernel(
    const float* __restrict__ x, const int* __restrict__ ei,
    float* __restrict__ agg, float* __restrict__ deg, int E)
{
    int e = blockIdx.x * 2 + (threadIdx.x >> 7);
    if (e >= E) return;
    int c = threadIdx.x & 127;
    int src = ei[e];        // row 0 of [2,E]
    int dst = ei[E + e];    // row 1
    float v = x[(size_t)src * IN_CH + c];
    atomicAdd(&agg[(size_t)dst * IN_CH + c], v);
    if (c == 0) atomicAdd(&deg[dst], 1.0f);
}

// ---------------- fused: out = relu(agg/deg @ Wl + x @ Wr + b) --------------
__global__ __launch_bounds__(256) void sage_gemm_kernel(
    const float* __restrict__ x, const float* __restrict__ agg,
    const float* __restrict__ deg,
    const float* __restrict__ Wl, const float* __restrict__ Wr,
    const float* __restrict__ bl,
    float* __restrict__ out, int N)
{
    __shared__ float sF[KB][LDSPAD];  // [k][n] transposed features
    __shared__ float sW[KB][LDSPAD];  // [k][j]

    const int tid   = threadIdx.x;
    const int nbase = blockIdx.x * TN;
    const int jbase = blockIdx.y * TJ;
    const int tcol  = tid & 15;   // channel quad
    const int trow  = tid >> 4;   // node quad

    float acc[4][4] = {};

    for (int kb = 0; kb < KTOT; kb += KB) {
        __syncthreads();
        // ---- stage weights: sW[k][j] = Wcat[kb+k][jbase+j], 32x64 floats ----
        #pragma unroll
        for (int p = 0; p < 2; ++p) {
            int idx = tid + p * 256;            // float4 index, 0..511
            int k   = idx >> 4;                 // 16 float4 per k-row
            int j4  = idx & 15;
            int gk  = kb + k;
            const float* W = (gk < IN_CH) ? (Wl + (size_t)gk * HID_CH)
                                          : (Wr + (size_t)(gk - IN_CH) * HID_CH);
            float4 v = *reinterpret_cast<const float4*>(W + jbase + j4 * 4);
            *reinterpret_cast<float4*>(&sW[k][j4 * 4]) = v;
        }
        // ---- stage features transposed: sF[k][n] = feat_cat[nbase+n][kb+k] ----
        #pragma unroll
        for (int p = 0; p < 2; ++p) {
            int idx = tid + p * 256;            // float4 index, 0..511
            int n   = idx >> 3;                 // 8 float4 per node
            int k4  = idx & 7;
            int gn  = nbase + n;
            int gnc = (gn < N) ? gn : (N - 1);  // clamp; stores guarded later
            int gk  = kb + k4 * 4;
            float4 v;
            float scale = 1.0f;
            if (gk < IN_CH) {
                v = *reinterpret_cast<const float4*>(agg + (size_t)gnc * IN_CH + gk);
                scale = 1.0f / fmaxf(deg[gnc], 1.0f);
            } else {
                v = *reinterpret_cast<const float4*>(x + (size_t)gnc * IN_CH + (gk - IN_CH));
            }
            int k = k4 * 4;
            sF[k + 0][n] = v.x * scale;
            sF[k + 1][n] = v.y * scale;
            sF[k + 2][n] = v.z * scale;
            sF[k + 3][n] = v.w * scale;
        }
        __syncthreads();
        // ---- 4x4 outer-product accumulate over this K chunk ----
        #pragma unroll
        for (int k = 0; k < KB; ++k) {
            float4 f = *reinterpret_cast<const float4*>(&sF[k][trow * 4]);
            float4 w = *reinterpret_cast<const float4*>(&sW[k][tcol * 4]);
            float fv[4] = {f.x, f.y, f.z, f.w};
            float wv[4] = {w.x, w.y, w.z, w.w};
            #pragma unroll
            for (int a = 0; a < 4; ++a)
                #pragma unroll
                for (int b = 0; b < 4; ++b)
                    acc[a][b] += fv[a] * wv[b];
        }
    }

    // ---- epilogue: bias + relu, guarded float4 stores ----
    float4 bias = *reinterpret_cast<const float4*>(bl + jbase + tcol * 4);
    float bv[4] = {bias.x, bias.y, bias.z, bias.w};
    #pragma unroll
    for (int a = 0; a < 4; ++a) {
        int gn = nbase + trow * 4 + a;
        if (gn < N) {
            float4 o;
            o.x = fmaxf(acc[a][0] + bv[0], 0.0f);
            o.y = fmaxf(acc[a][1] + bv[1], 0.0f);
            o.z = fmaxf(acc[a][2] + bv[2], 0.0f);
            o.w = fmaxf(acc[a][3] + bv[3], 0.0f);
            *reinterpret_cast<float4*>(out + (size_t)gn * HID_CH + jbase + tcol * 4) = o;
        }
    }
}

extern "C" void kernel_launch(void* const* d_in, const int* in_sizes, int n_in,
                              void* d_out, int out_size, void* d_ws, size_t ws_size,
                              hipStream_t stream) {
    const float* x  = (const float*)d_in[0];
    const int*   ei = (const int*)d_in[1];
    const float* Wl = (const float*)d_in[2];
    const float* bl = (const float*)d_in[3];
    const float* Wr = (const float*)d_in[4];
    float* out = (float*)d_out;

    const int N = in_sizes[0] / IN_CH;     // 50000
    const int E = in_sizes[1] / 2;         // 800000

    float* agg = (float*)d_ws;                       // N*IN_CH floats
    float* deg = agg + (size_t)N * IN_CH;            // N floats

    size_t zero_bytes = ((size_t)N * IN_CH + N) * sizeof(float);
    hipMemsetAsync(d_ws, 0, zero_bytes, stream);

    // scatter-add: 2 edges per 256-thread block
    int sblocks = (E + 1) / 2;
    scatter_kernel<<<sblocks, 256, 0, stream>>>(x, ei, agg, deg, E);

    // fused GEMM + bias + relu
    dim3 grid((N + TN - 1) / TN, HID_CH / TJ);
    sage_gemm_kernel<<<grid, 256, 0, stream>>>(x, agg, deg, Wl, Wr, bl, out, N);
}

// Round 2
// 266.105 us; speedup vs baseline: 1.8973x; 1.8973x over previous
//
#include <hip/hip_runtime.h>
#include <hip/hip_bf16.h>

#define IN_CH   128
#define HID_CH  256
#define KTOT    256   // concat K: [agg | x]
#define KB      32    // K chunk staged in LDS
#define TN      64    // nodes per block
#define TJ      64    // out channels per block
#define LDSPAD  68    // row stride in floats

// ---------------- degree count: deg[dst]++ ----------------
__global__ __launch_bounds__(256) void deg_count_kernel(
    const int* __restrict__ ei, int* __restrict__ deg, int E)
{
    int e = blockIdx.x * 256 + threadIdx.x;
    if (e < E) atomicAdd(&deg[ei[E + e]], 1);
}

// ---------------- scan pass 1: per-block exclusive scan + block totals ------
__global__ __launch_bounds__(256) void scan_block_kernel(
    const int* __restrict__ deg, int* __restrict__ rowptr,
    int* __restrict__ partials, int N)
{
    __shared__ int s[256];
    int t = threadIdx.x;
    int i = blockIdx.x * 256 + t;
    int v = (i < N) ? deg[i] : 0;
    s[t] = v;
    __syncthreads();
    #pragma unroll
    for (int off = 1; off < 256; off <<= 1) {
        int add = (t >= off) ? s[t - off] : 0;
        __syncthreads();
        s[t] += add;
        __syncthreads();
    }
    if (i < N) rowptr[i] = s[t] - v;          // local exclusive prefix
    if (t == 255) partials[blockIdx.x] = s[255];
}

// ---------------- scan pass 2: exclusive scan of block totals (nb<=256) -----
__global__ __launch_bounds__(256) void scan_partials_kernel(
    const int* __restrict__ partials, int* __restrict__ blockoff, int nb)
{
    __shared__ int s[256];
    int t = threadIdx.x;
    int v = (t < nb) ? partials[t] : 0;
    s[t] = v;
    __syncthreads();
    #pragma unroll
    for (int off = 1; off < 256; off <<= 1) {
        int add = (t >= off) ? s[t - off] : 0;
        __syncthreads();
        s[t] += add;
        __syncthreads();
    }
    if (t < nb) blockoff[t] = s[t] - v;
}

// ---------------- scan pass 3: add block offsets, init cursors --------------
__global__ __launch_bounds__(256) void add_offsets_kernel(
    int* __restrict__ rowptr, const int* __restrict__ blockoff,
    int* __restrict__ cursor, int N, int E)
{
    int i = blockIdx.x * 256 + threadIdx.x;
    if (i < N) {
        int r = rowptr[i] + blockoff[blockIdx.x];
        rowptr[i] = r;
        cursor[i] = r;
    }
    if (i == 0) rowptr[N] = E;
}

// ---------------- CSR fill: col[pos++] = src --------------------------------
__global__ __launch_bounds__(256) void csr_fill_kernel(
    const int* __restrict__ ei, int* __restrict__ cursor,
    int* __restrict__ col, int E)
{
    int e = blockIdx.x * 256 + threadIdx.x;
    if (e < E) {
        int dst = ei[E + e];
        int pos = atomicAdd(&cursor[dst], 1);
        col[pos] = ei[e];
    }
}

// ---------------- gather-mean: agg[n] = mean_{e in row n} x[col[e]] ---------
__global__ __launch_bounds__(256) void gather_mean_kernel(
    const float* __restrict__ x, const int* __restrict__ rowptr,
    const int* __restrict__ col, float* __restrict__ agg, int N)
{
    int w = blockIdx.x * 4 + (threadIdx.x >> 6);   // one wave per node
    if (w >= N) return;
    int lane = threadIdx.x & 63;
    int beg = rowptr[w], end = rowptr[w + 1];

    float ax = 0.0f, ay = 0.0f;
    int e = beg;
    for (; e + 4 <= end; e += 4) {
        int s0 = col[e], s1 = col[e + 1], s2 = col[e + 2], s3 = col[e + 3];
        float2 v0 = *reinterpret_cast<const float2*>(x + (size_t)s0 * IN_CH + lane * 2);
        float2 v1 = *reinterpret_cast<const float2*>(x + (size_t)s1 * IN_CH + lane * 2);
        float2 v2 = *reinterpret_cast<const float2*>(x + (size_t)s2 * IN_CH + lane * 2);
        float2 v3 = *reinterpret_cast<const float2*>(x + (size_t)s3 * IN_CH + lane * 2);
        ax += (v0.x + v1.x) + (v2.x + v3.x);
        ay += (v0.y + v1.y) + (v2.y + v3.y);
    }
    for (; e < end; ++e) {
        int s0 = col[e];
        float2 v = *reinterpret_cast<const float2*>(x + (size_t)s0 * IN_CH + lane * 2);
        ax += v.x; ay += v.y;
    }
    float inv = 1.0f / fmaxf((float)(end - beg), 1.0f);
    float2 o; o.x = ax * inv; o.y = ay * inv;
    *reinterpret_cast<float2*>(agg + (size_t)w * IN_CH + lane * 2) = o;
}

// ---------------- fused: out = relu(agg @ Wl + x @ Wr + b) ------------------
__global__ __launch_bounds__(256) void sage_gemm_kernel(
    const float* __restrict__ x, const float* __restrict__ agg,
    const float* __restrict__ Wl, const float* __restrict__ Wr,
    const float* __restrict__ bl,
    float* __restrict__ out, int N)
{
    __shared__ float sF[KB][LDSPAD];  // [k][n] transposed features
    __shared__ float sW[KB][LDSPAD];  // [k][j]

    const int tid   = threadIdx.x;
    const int nbase = blockIdx.x * TN;
    const int jbase = blockIdx.y * TJ;
    const int tcol  = tid & 15;   // channel quad
    const int trow  = tid >> 4;   // node quad

    float acc[4][4] = {};

    for (int kb = 0; kb < KTOT; kb += KB) {
        __syncthreads();
        // ---- stage weights: sW[k][j] = Wcat[kb+k][jbase+j] ----
        #pragma unroll
        for (int p = 0; p < 2; ++p) {
            int idx = tid + p * 256;            // float4 index, 0..511
            int k   = idx >> 4;
            int j4  = idx & 15;
            int gk  = kb + k;
            const float* W = (gk < IN_CH) ? (Wl + (size_t)gk * HID_CH)
                                          : (Wr + (size_t)(gk - IN_CH) * HID_CH);
            float4 v = *reinterpret_cast<const float4*>(W + jbase + j4 * 4);
            *reinterpret_cast<float4*>(&sW[k][j4 * 4]) = v;
        }
        // ---- stage features transposed: sF[k][n] = feat_cat[nbase+n][kb+k] ----
        #pragma unroll
        for (int p = 0; p < 2; ++p) {
            int idx = tid + p * 256;
            int n   = idx >> 3;
            int k4  = idx & 7;
            int gn  = nbase + n;
            int gnc = (gn < N) ? gn : (N - 1);
            int gk  = kb + k4 * 4;
            float4 v;
            if (gk < IN_CH) {
                v = *reinterpret_cast<const float4*>(agg + (size_t)gnc * IN_CH + gk);
            } else {
                v = *reinterpret_cast<const float4*>(x + (size_t)gnc * IN_CH + (gk - IN_CH));
            }
            int k = k4 * 4;
            sF[k + 0][n] = v.x;
            sF[k + 1][n] = v.y;
            sF[k + 2][n] = v.z;
            sF[k + 3][n] = v.w;
        }
        __syncthreads();
        // ---- 4x4 outer-product accumulate ----
        #pragma unroll
        for (int k = 0; k < KB; ++k) {
            float4 f = *reinterpret_cast<const float4*>(&sF[k][trow * 4]);
            float4 w = *reinterpret_cast<const float4*>(&sW[k][tcol * 4]);
            float fv[4] = {f.x, f.y, f.z, f.w};
            float wv[4] = {w.x, w.y, w.z, w.w};
            #pragma unroll
            for (int a = 0; a < 4; ++a)
                #pragma unroll
                for (int b = 0; b < 4; ++b)
                    acc[a][b] += fv[a] * wv[b];
        }
    }

    // ---- epilogue: bias + relu, guarded float4 stores ----
    float4 bias = *reinterpret_cast<const float4*>(bl + jbase + tcol * 4);
    float bv[4] = {bias.x, bias.y, bias.z, bias.w};
    #pragma unroll
    for (int a = 0; a < 4; ++a) {
        int gn = nbase + trow * 4 + a;
        if (gn < N) {
            float4 o;
            o.x = fmaxf(acc[a][0] + bv[0], 0.0f);
            o.y = fmaxf(acc[a][1] + bv[1], 0.0f);
            o.z = fmaxf(acc[a][2] + bv[2], 0.0f);
            o.w = fmaxf(acc[a][3] + bv[3], 0.0f);
            *reinterpret_cast<float4*>(out + (size_t)gn * HID_CH + jbase + tcol * 4) = o;
        }
    }
}

extern "C" void kernel_launch(void* const* d_in, const int* in_sizes, int n_in,
                              void* d_out, int out_size, void* d_ws, size_t ws_size,
                              hipStream_t stream) {
    const float* x  = (const float*)d_in[0];
    const int*   ei = (const int*)d_in[1];
    const float* Wl = (const float*)d_in[2];
    const float* bl = (const float*)d_in[3];
    const float* Wr = (const float*)d_in[4];
    float* out = (float*)d_out;

    const int N = in_sizes[0] / IN_CH;     // 50000
    const int E = in_sizes[1] / 2;         // 800000

    // workspace layout
    float* agg     = (float*)d_ws;                       // N*IN_CH floats
    int*   deg     = (int*)(agg + (size_t)N * IN_CH);    // N
    int*   rowptr  = deg + N;                            // N+1
    int*   cursor  = rowptr + N + 1;                     // N
    int*   col     = cursor + N;                         // E
    int*   partials= col + E;                            // 256
    int*   blockoff= partials + 256;                     // 256

    hipMemsetAsync(deg, 0, (size_t)N * sizeof(int), stream);

    const int NB = (N + 255) / 256;        // 196 blocks (<=256 for pass 2)
    const int EB = (E + 255) / 256;

    deg_count_kernel<<<EB, 256, 0, stream>>>(ei, deg, E);
    scan_block_kernel<<<NB, 256, 0, stream>>>(deg, rowptr, partials, N);
    scan_partials_kernel<<<1, 256, 0, stream>>>(partials, blockoff, NB);
    add_offsets_kernel<<<NB, 256, 0, stream>>>(rowptr, blockoff, cursor, N, E);
    csr_fill_kernel<<<EB, 256, 0, stream>>>(ei, cursor, col, E);
    gather_mean_kernel<<<(N + 3) / 4, 256, 0, stream>>>(x, rowptr, col, agg, N);

    dim3 grid((N + TN - 1) / TN, HID_CH / TJ);
    sage_gemm_kernel<<<grid, 256, 0, stream>>>(x, agg, Wl, Wr, bl, out, N);
}

// Round 3
// 188.481 us; speedup vs baseline: 2.6786x; 1.4118x over previous
//
#include <hip/hip_runtime.h>
#include <hip/hip_bf16.h>

#define IN_CH   128
#define HID_CH  256
#define KTOT    256           // concat K: [agg | x]
#define LDS_RS  72            // LDS row stride in shorts (64 data + 8 pad, 144B = 9*16B)

typedef __attribute__((ext_vector_type(8))) short bf16x8;
typedef __attribute__((ext_vector_type(4))) float f32x4;

static __device__ __forceinline__ unsigned short f2bf(float f) {
    unsigned int u = __float_as_uint(f);
    unsigned int r = (u + 0x7FFFu + ((u >> 16) & 1u)) >> 16;   // RNE
    return (unsigned short)r;
}
static __device__ __forceinline__ float bf2f(unsigned int ubits16) {
    return __uint_as_float(ubits16 << 16);
}

// ---------------- convert x -> bf16 into featb[:,128:256] -------------------
__global__ __launch_bounds__(256) void convert_x_kernel(
    const float* __restrict__ x, unsigned short* __restrict__ featb, int N)
{
    int t = blockIdx.x * 256 + threadIdx.x;          // one thread = 8 floats
    if (t >= N * 16) return;
    int n = t >> 4, c8 = (t & 15) * 8;
    const float* src = x + (size_t)n * IN_CH + c8;
    float4 v0 = *reinterpret_cast<const float4*>(src);
    float4 v1 = *reinterpret_cast<const float4*>(src + 4);
    uint4 o;
    o.x = (unsigned)f2bf(v0.x) | ((unsigned)f2bf(v0.y) << 16);
    o.y = (unsigned)f2bf(v0.z) | ((unsigned)f2bf(v0.w) << 16);
    o.z = (unsigned)f2bf(v1.x) | ((unsigned)f2bf(v1.y) << 16);
    o.w = (unsigned)f2bf(v1.z) | ((unsigned)f2bf(v1.w) << 16);
    *reinterpret_cast<uint4*>(featb + (size_t)n * KTOT + IN_CH + c8) = o;
}

// ---------------- convert weights -> WT[n][k] bf16 (K-contiguous, concat) ---
__global__ __launch_bounds__(256) void convert_w_kernel(
    const float* __restrict__ Wl, const float* __restrict__ Wr,
    unsigned short* __restrict__ WT)
{
    int t = blockIdx.x * 256 + threadIdx.x;          // 65536 total
    int n = t >> 8, k = t & 255;
    float v = (k < IN_CH) ? Wl[(size_t)k * HID_CH + n]
                          : Wr[(size_t)(k - IN_CH) * HID_CH + n];
    WT[(size_t)n * KTOT + k] = f2bf(v);
}

// ---------------- degree count: deg[dst]++ ----------------------------------
__global__ __launch_bounds__(256) void deg_count_kernel(
    const int* __restrict__ ei, int* __restrict__ deg, int E)
{
    int e = blockIdx.x * 256 + threadIdx.x;
    if (e < E) atomicAdd(&deg[ei[E + e]], 1);
}

// ---------------- scan pass 1 ----------------------------------------------
__global__ __launch_bounds__(256) void scan_block_kernel(
    const int* __restrict__ deg, int* __restrict__ rowptr,
    int* __restrict__ partials, int N)
{
    __shared__ int s[256];
    int t = threadIdx.x;
    int i = blockIdx.x * 256 + t;
    int v = (i < N) ? deg[i] : 0;
    s[t] = v;
    __syncthreads();
    #pragma unroll
    for (int off = 1; off < 256; off <<= 1) {
        int add = (t >= off) ? s[t - off] : 0;
        __syncthreads();
        s[t] += add;
        __syncthreads();
    }
    if (i < N) rowptr[i] = s[t] - v;
    if (t == 255) partials[blockIdx.x] = s[255];
}

// ---------------- scan pass 2 (nb<=256) -------------------------------------
__global__ __launch_bounds__(256) void scan_partials_kernel(
    const int* __restrict__ partials, int* __restrict__ blockoff, int nb)
{
    __shared__ int s[256];
    int t = threadIdx.x;
    int v = (t < nb) ? partials[t] : 0;
    s[t] = v;
    __syncthreads();
    #pragma unroll
    for (int off = 1; off < 256; off <<= 1) {
        int add = (t >= off) ? s[t - off] : 0;
        __syncthreads();
        s[t] += add;
        __syncthreads();
    }
    if (t < nb) blockoff[t] = s[t] - v;
}

// ---------------- scan pass 3 ------------------------------------------------
__global__ __launch_bounds__(256) void add_offsets_kernel(
    int* __restrict__ rowptr, const int* __restrict__ blockoff,
    int* __restrict__ cursor, int N, int E)
{
    int i = blockIdx.x * 256 + threadIdx.x;
    if (i < N) {
        int r = rowptr[i] + blockoff[blockIdx.x];
        rowptr[i] = r;
        cursor[i] = r;
    }
    if (i == 0) rowptr[N] = E;
}

// ---------------- CSR fill ----------------------------------------------------
__global__ __launch_bounds__(256) void csr_fill_kernel(
    const int* __restrict__ ei, int* __restrict__ cursor,
    int* __restrict__ col, int E)
{
    int e = blockIdx.x * 256 + threadIdx.x;
    if (e < E) {
        int dst = ei[E + e];
        int pos = atomicAdd(&cursor[dst], 1);
        col[pos] = ei[e];
    }
}

// ---------------- gather-mean over bf16 x-half, write bf16 agg-half ----------
__global__ __launch_bounds__(256) void gather_mean_kernel(
    unsigned short* __restrict__ featb, const int* __restrict__ rowptr,
    const int* __restrict__ col, int N)
{
    int w = blockIdx.x * 4 + (threadIdx.x >> 6);   // one wave per node
    if (w >= N) return;
    int lane = threadIdx.x & 63;
    int beg = rowptr[w], end = rowptr[w + 1];

    float ax = 0.0f, ay = 0.0f;
    int e = beg;
    for (; e + 4 <= end; e += 4) {
        int s0 = col[e], s1 = col[e + 1], s2 = col[e + 2], s3 = col[e + 3];
        unsigned u0 = *reinterpret_cast<const unsigned*>(featb + (size_t)s0 * KTOT + IN_CH + lane * 2);
        unsigned u1 = *reinterpret_cast<const unsigned*>(featb + (size_t)s1 * KTOT + IN_CH + lane * 2);
        unsigned u2 = *reinterpret_cast<const unsigned*>(featb + (size_t)s2 * KTOT + IN_CH + lane * 2);
        unsigned u3 = *reinterpret_cast<const unsigned*>(featb + (size_t)s3 * KTOT + IN_CH + lane * 2);
        ax += (bf2f(u0 & 0xFFFF) + bf2f(u1 & 0xFFFF)) + (bf2f(u2 & 0xFFFF) + bf2f(u3 & 0xFFFF));
        ay += (bf2f(u0 >> 16)    + bf2f(u1 >> 16))    + (bf2f(u2 >> 16)    + bf2f(u3 >> 16));
    }
    for (; e < end; ++e) {
        unsigned u = *reinterpret_cast<const unsigned*>(featb + (size_t)col[e] * KTOT + IN_CH + lane * 2);
        ax += bf2f(u & 0xFFFF);
        ay += bf2f(u >> 16);
    }
    float inv = 1.0f / fmaxf((float)(end - beg), 1.0f);
    unsigned o = (unsigned)f2bf(ax * inv) | ((unsigned)f2bf(ay * inv) << 16);
    *reinterpret_cast<unsigned*>(featb + (size_t)w * KTOT + lane * 2) = o;
}

// ---------------- MFMA GEMM: out = relu(featb @ Wcat + b) --------------------
// featb [Npad][256] bf16, WT [256][256] bf16 (n-major, K-contiguous)
__global__ __launch_bounds__(256) void sage_mfma_kernel(
    const unsigned short* __restrict__ featb,
    const unsigned short* __restrict__ WT,
    const float* __restrict__ bl,
    float* __restrict__ out, int N)
{
    __shared__ unsigned short sA[128][LDS_RS];
    __shared__ unsigned short sB[128][LDS_RS];

    const int tid   = threadIdx.x;
    const int nbase = blockIdx.x * 128;
    const int jbase = blockIdx.y * 128;
    const int lane  = tid & 63;
    const int w     = tid >> 6;            // wave id, 2x2 grid of 64x64
    const int wr    = (w >> 1) * 64;
    const int wc    = (w & 1) * 64;
    const int lr    = lane & 15;
    const int lk    = (lane >> 4) * 8;     // k-offset within fragment

    f32x4 acc[4][4] = {};

    for (int kb = 0; kb < KTOT; kb += 64) {
        __syncthreads();
        // stage A (feat rows) and B (WT rows), 128 rows x 64 k each
        #pragma unroll
        for (int p = 0; p < 4; ++p) {
            int c = tid + p * 256;             // 16B chunk id, 0..1023
            int row = c >> 3, q = c & 7;
            uint4 va = *reinterpret_cast<const uint4*>(
                featb + (size_t)(nbase + row) * KTOT + kb + q * 8);
            *reinterpret_cast<uint4*>(&sA[row][q * 8]) = va;
            uint4 vb = *reinterpret_cast<const uint4*>(
                WT + (size_t)(jbase + row) * KTOT + kb + q * 8);
            *reinterpret_cast<uint4*>(&sB[row][q * 8]) = vb;
        }
        __syncthreads();
        #pragma unroll
        for (int ks = 0; ks < 2; ++ks) {
            bf16x8 af[4], bfr[4];
            #pragma unroll
            for (int i = 0; i < 4; ++i) {
                af[i]  = *reinterpret_cast<const bf16x8*>(&sA[wr + i * 16 + lr][ks * 32 + lk]);
                bfr[i] = *reinterpret_cast<const bf16x8*>(&sB[wc + i * 16 + lr][ks * 32 + lk]);
            }
            #pragma unroll
            for (int mi = 0; mi < 4; ++mi)
                #pragma unroll
                for (int ni = 0; ni < 4; ++ni)
                    acc[mi][ni] = __builtin_amdgcn_mfma_f32_16x16x32_bf16(
                        af[mi], bfr[ni], acc[mi][ni], 0, 0, 0);
        }
    }

    // epilogue: bias + relu; C/D layout col=lane&15, row=(lane>>4)*4+reg
    #pragma unroll
    for (int ni = 0; ni < 4; ++ni) {
        float bias = bl[jbase + wc + ni * 16 + lr];
        #pragma unroll
        for (int mi = 0; mi < 4; ++mi) {
            #pragma unroll
            for (int r = 0; r < 4; ++r) {
                int row = nbase + wr + mi * 16 + (lane >> 4) * 4 + r;
                if (row < N) {
                    int colj = jbase + wc + ni * 16 + lr;
                    out[(size_t)row * HID_CH + colj] = fmaxf(acc[mi][ni][r] + bias, 0.0f);
                }
            }
        }
    }
}

extern "C" void kernel_launch(void* const* d_in, const int* in_sizes, int n_in,
                              void* d_out, int out_size, void* d_ws, size_t ws_size,
                              hipStream_t stream) {
    const float* x  = (const float*)d_in[0];
    const int*   ei = (const int*)d_in[1];
    const float* Wl = (const float*)d_in[2];
    const float* bl = (const float*)d_in[3];
    const float* Wr = (const float*)d_in[4];
    float* out = (float*)d_out;

    const int N = in_sizes[0] / IN_CH;     // 50000
    const int E = in_sizes[1] / 2;         // 800000
    const int Npad = ((N + 127) / 128) * 128;

    // workspace layout
    unsigned short* featb = (unsigned short*)d_ws;          // Npad*256 bf16
    unsigned short* WT    = featb + (size_t)Npad * KTOT;    // 256*256 bf16
    int* deg      = (int*)(WT + KTOT * HID_CH);             // N
    int* rowptr   = deg + N;                                // N+1
    int* cursor   = rowptr + N + 1;                         // N
    int* col      = cursor + N;                             // E
    int* partials = col + E;                                // 256
    int* blockoff = partials + 256;                         // 256

    hipMemsetAsync(deg, 0, (size_t)N * sizeof(int), stream);
    if (Npad > N)   // zero tail rows so GEMM staging reads clean data
        hipMemsetAsync(featb + (size_t)N * KTOT, 0,
                       (size_t)(Npad - N) * KTOT * sizeof(unsigned short), stream);

    const int NB = (N + 255) / 256;
    const int EB = (E + 255) / 256;

    convert_x_kernel<<<(N * 16 + 255) / 256, 256, 0, stream>>>(x, featb, N);
    convert_w_kernel<<<(KTOT * HID_CH) / 256, 256, 0, stream>>>(Wl, Wr, WT);
    deg_count_kernel<<<EB, 256, 0, stream>>>(ei, deg, E);
    scan_block_kernel<<<NB, 256, 0, stream>>>(deg, rowptr, partials, N);
    scan_partials_kernel<<<1, 256, 0, stream>>>(partials, blockoff, NB);
    add_offsets_kernel<<<NB, 256, 0, stream>>>(rowptr, blockoff, cursor, N, E);
    csr_fill_kernel<<<EB, 256, 0, stream>>>(ei, cursor, col, E);
    gather_mean_kernel<<<(N + 3) / 4, 256, 0, stream>>>(featb, rowptr, col, N);

    dim3 grid(Npad / 128, HID_CH / 128);
    sage_mfma_kernel<<<grid, 256, 0, stream>>>(featb, WT, bl, out, N);
}